// Round 1
// baseline (8689.667 us; speedup 1.0000x reference)
//
#include <hip/hip_runtime.h>
#include <hip/hip_bf16.h>
#include <math.h>

// Problem constants (from reference setup_inputs)
#define BB 4
#define SS 512
#define HH 2048
#define EE 16
#define DD 128
#define GH 2048           // E*D
#define G3 6144           // 3*GH
#define NTOK 2048         // B*S

// ---------------- GEMM 1: C[M,N] = A[M,K] * B[N,K]^T  (both K-major) --------
// Used for xi = x @ w_ih^T.  M=2048, N=6144, K=2048. Tile 64x64, BK=16.
__global__ __launch_bounds__(256) void gemm_abt(const float* __restrict__ A,
                                                const float* __restrict__ B,
                                                float* __restrict__ C,
                                                int M, int N, int K) {
  __shared__ float As[16][65];
  __shared__ float Bs[16][65];
  const int bm = blockIdx.y * 64, bn = blockIdx.x * 64;
  const int tid = threadIdx.x;
  const int tx = tid & 15, ty = tid >> 4;
  const int lc = tid & 15;   // k within tile
  const int lr = tid >> 4;   // row group
  float acc[4][4] = {};
  for (int k0 = 0; k0 < K; k0 += 16) {
#pragma unroll
    for (int i = 0; i < 4; ++i) {
      int m = lr + i * 16;
      As[lc][m] = A[(size_t)(bm + m) * K + k0 + lc];
      Bs[lc][m] = B[(size_t)(bn + m) * K + k0 + lc];
    }
    __syncthreads();
#pragma unroll
    for (int kk = 0; kk < 16; ++kk) {
      float a[4], b[4];
#pragma unroll
      for (int i = 0; i < 4; ++i) a[i] = As[kk][ty * 4 + i];
#pragma unroll
      for (int j = 0; j < 4; ++j) b[j] = Bs[kk][tx * 4 + j];
#pragma unroll
      for (int i = 0; i < 4; ++i)
#pragma unroll
        for (int j = 0; j < 4; ++j) acc[i][j] = fmaf(a[i], b[j], acc[i][j]);
    }
    __syncthreads();
  }
#pragma unroll
  for (int i = 0; i < 4; ++i)
#pragma unroll
    for (int j = 0; j < 4; ++j)
      C[(size_t)(bm + ty * 4 + i) * N + bn + tx * 4 + j] = acc[i][j];
}

// ---------------- GEMM 2: C[M,N] = A[M,K] * B[K,N] ---------------------------
// Used for expression_logits = x @ w_expr. M=2048, N=2048, K=2048.
__global__ __launch_bounds__(256) void gemm_ab(const float* __restrict__ A,
                                               const float* __restrict__ B,
                                               float* __restrict__ C,
                                               int M, int N, int K) {
  __shared__ float As[16][65];
  __shared__ float Bs[16][65];
  const int bm = blockIdx.y * 64, bn = blockIdx.x * 64;
  const int tid = threadIdx.x;
  const int tx = tid & 15, ty = tid >> 4;
  const int lc = tid & 15;
  const int lr = tid >> 4;
  const int nn = tid & 63;    // col for B load
  const int kb = tid >> 6;    // 0..3
  float acc[4][4] = {};
  for (int k0 = 0; k0 < K; k0 += 16) {
#pragma unroll
    for (int i = 0; i < 4; ++i) {
      int m = lr + i * 16;
      As[lc][m] = A[(size_t)(bm + m) * K + k0 + lc];
      Bs[kb + i * 4][nn] = B[(size_t)(k0 + kb + i * 4) * N + bn + nn];
    }
    __syncthreads();
#pragma unroll
    for (int kk = 0; kk < 16; ++kk) {
      float a[4], b[4];
#pragma unroll
      for (int i = 0; i < 4; ++i) a[i] = As[kk][ty * 4 + i];
#pragma unroll
      for (int j = 0; j < 4; ++j) b[j] = Bs[kk][tx * 4 + j];
#pragma unroll
      for (int i = 0; i < 4; ++i)
#pragma unroll
        for (int j = 0; j < 4; ++j) acc[i][j] = fmaf(a[i], b[j], acc[i][j]);
    }
    __syncthreads();
  }
#pragma unroll
  for (int i = 0; i < 4; ++i)
#pragma unroll
    for (int j = 0; j < 4; ++j)
      C[(size_t)(bm + ty * 4 + i) * N + bn + tx * 4 + j] = acc[i][j];
}

// ---------------- A^T*A loss: sum over (i,j) of (gw[i][j]-I)^2 ---------------
// A = w_expr [K=2048 rows][N=2048 cols]. Never materializes gw.
__global__ __launch_bounds__(256) void ata_loss(const float* __restrict__ A,
                                                float* __restrict__ el_accum,
                                                int N, int K) {
  __shared__ float As[16][65];
  __shared__ float Bs[16][65];
  __shared__ float red[256];
  const int bi = blockIdx.y * 64, bj = blockIdx.x * 64;
  const int tid = threadIdx.x;
  const int tx = tid & 15, ty = tid >> 4;
  const int nn = tid & 63;
  const int kb = tid >> 6;
  float acc[4][4] = {};
  for (int k0 = 0; k0 < K; k0 += 16) {
#pragma unroll
    for (int i = 0; i < 4; ++i) {
      As[kb + i * 4][nn] = A[(size_t)(k0 + kb + i * 4) * N + bi + nn];
      Bs[kb + i * 4][nn] = A[(size_t)(k0 + kb + i * 4) * N + bj + nn];
    }
    __syncthreads();
#pragma unroll
    for (int kk = 0; kk < 16; ++kk) {
      float a[4], b[4];
#pragma unroll
      for (int i = 0; i < 4; ++i) a[i] = As[kk][ty * 4 + i];
#pragma unroll
      for (int j = 0; j < 4; ++j) b[j] = Bs[kk][tx * 4 + j];
#pragma unroll
      for (int i = 0; i < 4; ++i)
#pragma unroll
        for (int j = 0; j < 4; ++j) acc[i][j] = fmaf(a[i], b[j], acc[i][j]);
    }
    __syncthreads();
  }
  float local = 0.f;
#pragma unroll
  for (int i = 0; i < 4; ++i) {
#pragma unroll
    for (int j = 0; j < 4; ++j) {
      int gi = bi + ty * 4 + i, gj = bj + tx * 4 + j;
      float d = acc[i][j] - ((gi == gj) ? 1.0f : 0.0f);
      local += d * d;
    }
  }
  red[tid] = local;
  __syncthreads();
  for (int s = 128; s > 0; s >>= 1) {
    if (tid < s) red[tid] += red[tid + s];
    __syncthreads();
  }
  if (tid == 0) atomicAdd(el_accum, red[0]);
}

// ---------------- GRU step -----------------------------------------------
__device__ inline float wred64(float v) {
#pragma unroll
  for (int o = 32; o; o >>= 1) v += __shfl_xor(v, o);
  return v;
}

// One step: for all b, j: r/z/n gates + h update. 512 blocks x 256 thr.
// Each wave handles one j for all 4 batches (reads each w_hh row exactly once).
__global__ __launch_bounds__(256) void gru_step(const float* __restrict__ xi,   // [B,S,3GH]
                                                const float* __restrict__ w_hh, // [3GH,GH]
                                                float* __restrict__ hs,         // [B,S,GH]
                                                const float* __restrict__ hn,   // [1,B,GH]
                                                int s) {
  __shared__ __align__(16) float hsm[BB * GH];  // 32 KB
  const int tid = threadIdx.x;
  // stage h_prev for all 4 batches into LDS
#pragma unroll
  for (int b = 0; b < BB; ++b) {
    const float* hp = (s == 0) ? (hn + b * GH)
                               : (hs + ((size_t)(b * SS + s - 1)) * GH);
#pragma unroll
    for (int i = 0; i < 2; ++i) {
      int idx = (i * 256 + tid) * 4;
      *(float4*)(&hsm[b * GH + idx]) = *(const float4*)(hp + idx);
    }
  }
  __syncthreads();

  const int wave = tid >> 6, lane = tid & 63;
  const int j = blockIdx.x * 4 + wave;
  const float* wr = w_hh + (size_t)j * GH;
  const float* wz = w_hh + (size_t)(GH + j) * GH;
  const float* wn = w_hh + (size_t)(2 * GH + j) * GH;

  float ar[BB] = {}, az[BB] = {}, an[BB] = {};
#pragma unroll
  for (int i = 0; i < 8; ++i) {
    int k = (i * 64 + lane) * 4;
    float4 r4 = *(const float4*)(wr + k);
    float4 z4 = *(const float4*)(wz + k);
    float4 n4 = *(const float4*)(wn + k);
#pragma unroll
    for (int b = 0; b < BB; ++b) {
      float4 h4 = *(const float4*)(&hsm[b * GH + k]);
      ar[b] = fmaf(r4.x, h4.x, fmaf(r4.y, h4.y, fmaf(r4.z, h4.z, fmaf(r4.w, h4.w, ar[b]))));
      az[b] = fmaf(z4.x, h4.x, fmaf(z4.y, h4.y, fmaf(z4.z, h4.z, fmaf(z4.w, h4.w, az[b]))));
      an[b] = fmaf(n4.x, h4.x, fmaf(n4.y, h4.y, fmaf(n4.z, h4.z, fmaf(n4.w, h4.w, an[b]))));
    }
  }
#pragma unroll
  for (int b = 0; b < BB; ++b) {
    ar[b] = wred64(ar[b]);
    az[b] = wred64(az[b]);
    an[b] = wred64(an[b]);
  }
  if (lane == 0) {
#pragma unroll
    for (int b = 0; b < BB; ++b) {
      const float* xrow = xi + ((size_t)(b * SS + s)) * G3;
      float xr = xrow[j], xz = xrow[GH + j], xn = xrow[2 * GH + j];
      float r = 1.0f / (1.0f + expf(-(xr + ar[b])));
      float z = 1.0f / (1.0f + expf(-(xz + az[b])));
      float n = tanhf(xn + r * an[b]);
      float hp = hsm[b * GH + j];
      hs[((size_t)(b * SS + s)) * GH + j] = (1.0f - z) * n + z * hp;
    }
  }
}

// ---------------- per-token: normalize, gram/speciality, cosine --------------
__device__ inline float red16(float v) {
#pragma unroll
  for (int o = 8; o; o >>= 1) v += __shfl_xor(v, o);
  return v;
}

__global__ __launch_bounds__(256) void token_kernel(const float* __restrict__ hs,
                                                    const float* __restrict__ expr,   // d_out expr chunk
                                                    float* __restrict__ cos_out,
                                                    float* __restrict__ sp_accum) {
  __shared__ float routn[EE * 132];   // padded stride 132
  __shared__ float rowc[EE];
  const int t = blockIdx.x;           // token = b*S+s
  const int tid = threadIdx.x;
  const int e = tid >> 4, sub = tid & 15;

  const float* rrow = hs + (size_t)t * GH + e * DD + sub * 8;
  float rv[8];
#pragma unroll
  for (int i = 0; i < 8; ++i) rv[i] = rrow[i];
  float ss = 0.f;
#pragma unroll
  for (int i = 0; i < 8; ++i) ss += rv[i] * rv[i];
  ss = red16(ss);
  float inv = 1.0f / fmaxf(sqrtf(ss), 1e-12f);
#pragma unroll
  for (int i = 0; i < 8; ++i) {
    rv[i] *= inv;
    routn[e * 132 + sub * 8 + i] = rv[i];
  }

  // cosine sim with expression logits (rn of normalized rout == 1)
  const float* erow = expr + (size_t)t * GH + e * DD + sub * 8;
  float en2 = 0.f, dot = 0.f;
#pragma unroll
  for (int i = 0; i < 8; ++i) {
    float ev = erow[i];
    en2 += ev * ev;
    dot += ev * rv[i];
  }
  en2 = red16(en2);
  dot = red16(dot);
  if (sub == 0) {
    float cosv = dot / fmaxf(sqrtf(en2), 1e-8f);
    cos_out[t * EE + e] = 1.0f - cosv;
  }
  __syncthreads();

  // gram: thread (e,f) computes dot of normalized rows e,f over D
  const int f = sub;
  float g = 0.f;
#pragma unroll
  for (int d = 0; d < DD; ++d)
    g = fmaf(routn[e * 132 + d], routn[f * 132 + d], g);
  float diff = g - ((e == f) ? 1.0f : 0.0f);
  float rowsum = red16(diff * diff);          // sum over f of diff^2, per row e
  if (f == 0) {
    float nrm = fmaxf(sqrtf(rowsum), 1e-12f);
    rowc[e] = rowsum / (nrm * nrm);           // == sum of normalized-row squares
  }
  __syncthreads();
  if (tid == 0) {
    float tok = 0.f;
#pragma unroll
    for (int i = 0; i < EE; ++i) tok += rowc[i];
    atomicAdd(sp_accum, tok);
  }
}

// ---------------- final: top-2 + softmax + EMA adjust + hn copy + scalars ----
__global__ __launch_bounds__(256) void final_kernel(const float* __restrict__ hs,
                                                    const float* __restrict__ cos_out,
                                                    const float* __restrict__ ema,
                                                    const float* __restrict__ accum,
                                                    float* __restrict__ out_mult,
                                                    float* __restrict__ out_sel,
                                                    float* __restrict__ out_hn,
                                                    float* __restrict__ out_sp,
                                                    float* __restrict__ out_el) {
  const int gtid = blockIdx.x * 256 + threadIdx.x;
  // hn copy: 8192 elements
  if (gtid < BB * GH) {
    int b = gtid / GH, jj = gtid % GH;
    out_hn[gtid] = hs[((size_t)(b * SS + SS - 1)) * GH + jj];
  }
  if (gtid < NTOK) {
    float sp = accum[0] / (float)NTOK;
    float scale = 1.0f + sp;
    float dv[EE];
#pragma unroll
    for (int e = 0; e < EE; ++e) dv[e] = cos_out[gtid * EE + e] * scale;
    int i0 = 0; float v0 = dv[0];
#pragma unroll
    for (int e = 1; e < EE; ++e) { if (dv[e] > v0) { v0 = dv[e]; i0 = e; } }
    int i1 = -1; float v1 = -1e30f;
#pragma unroll
    for (int e = 0; e < EE; ++e) { if (e != i0 && dv[e] > v1) { v1 = dv[e]; i1 = e; } }
    // stable softmax over [v0, v1] (v0 >= v1)
    float ex = expf(v1 - v0);
    float den = 1.0f + ex;
    float m0 = 1.0f / den, m1 = ex / den;
    float total = 0.f;
#pragma unroll
    for (int e = 0; e < EE; ++e) total += ema[e];
    float a0 = 0.f, a1 = 0.f;
    if (total > 0.f) {
      float invt = 1.0f / fmaxf(total, 1e-12f);
      a0 = ema[i0] * invt * 0.01f * (float)EE;
      a1 = ema[i1] * invt * 0.01f * (float)EE;
    }
    out_mult[gtid * 2 + 0] = m0 - a0;
    out_mult[gtid * 2 + 1] = m1 - a1;
    out_sel[gtid * 2 + 0] = (float)i0;
    out_sel[gtid * 2 + 1] = (float)i1;
  }
  if (gtid == 0) {
    out_sp[0] = accum[0] / (float)NTOK;
    out_el[0] = accum[1] / (float)(GH * GH);
  }
}

extern "C" void kernel_launch(void* const* d_in, const int* in_sizes, int n_in,
                              void* d_out, int out_size, void* d_ws, size_t ws_size,
                              hipStream_t stream) {
  const float* x      = (const float*)d_in[0];  // [B,S,H]
  const float* hn     = (const float*)d_in[1];  // [1,B,GH]
  const float* w_ih   = (const float*)d_in[2];  // [3GH,H]
  const float* w_hh   = (const float*)d_in[3];  // [3GH,GH]
  const float* w_expr = (const float*)d_in[4];  // [H,GH]
  const float* ema    = (const float*)d_in[5];  // [E]
  float* out = (float*)d_out;

  // output layout (fp32 elements), top_k = 2
  float* out_mult = out;                 // 4096
  float* out_sel  = out + 4096;          // 4096
  float* out_expr = out + 8192;          // 4194304
  float* out_hn   = out + 4202496;       // 8192
  float* out_sp   = out + 4210688;       // 1
  float* out_cos  = out + 4210689;       // 32768
  float* out_el   = out + 4243457;       // 1

  float* ws = (float*)d_ws;
  float* xi    = ws;                     // [B,S,3GH] 12,582,912 floats
  float* hs    = ws + 12582912;          // [B,S,GH]   4,194,304 floats
  float* accum = ws + 16777216;          // [0]=sp_sum, [1]=el_sum

  hipMemsetAsync(accum, 0, 2 * sizeof(float), stream);

  // xi = x @ w_ih^T   (M=2048, N=6144, K=2048)
  gemm_abt<<<dim3(G3 / 64, NTOK / 64), 256, 0, stream>>>(x, w_ih, xi, NTOK, G3, HH);

  // expression_logits = x @ w_expr   (M=2048, N=2048, K=2048) -> straight to d_out
  gemm_ab<<<dim3(GH / 64, NTOK / 64), 256, 0, stream>>>(x, w_expr, out_expr, NTOK, GH, HH);

  // GRU recurrence: 512 sequential steps
  for (int s = 0; s < SS; ++s)
    gru_step<<<GH / 4, 256, 0, stream>>>(xi, w_hh, hs, hn, s);

  // expression orthogonality loss
  ata_loss<<<dim3(GH / 64, GH / 64), 256, 0, stream>>>(w_expr, accum + 1, GH, HH);

  // per-token speciality + cosine
  token_kernel<<<NTOK, 256, 0, stream>>>(hs, out_expr, out_cos, accum);

  // final routing + copies + scalars
  final_kernel<<<(BB * GH + 255) / 256, 256, 0, stream>>>(hs, out_cos, ema, accum,
                                                          out_mult, out_sel, out_hn,
                                                          out_sp, out_el);
}